// Round 1
// baseline (65.509 us; speedup 1.0000x reference)
//
#include <hip/hip_runtime.h>
#include <math.h>

#define HWP   3136   // 56*56
#define W56   56
#define PITCH 58     // padded tile pitch
#define NF4   784    // 3136/4

__global__ __launch_bounds__(256) void dwconv3x3_q(
    const float* __restrict__ x, const float* __restrict__ wgt,
    float* __restrict__ out, int C)
{
    __shared__ float tile[PITCH * PITCH];   // 58*58 = 3364 floats = 13456 B
    __shared__ float wq[9];

    const int tid   = threadIdx.x;
    const int plane = blockIdx.x;           // b*C + c
    const int c     = plane % C;

    // zero the halo border of the padded tile
    if (tid < PITCH) {
        tile[tid] = 0.f;                              // top row
        tile[(PITCH - 1) * PITCH + tid] = 0.f;        // bottom row
        tile[tid * PITCH] = 0.f;                      // left col
        tile[tid * PITCH + (PITCH - 1)] = 0.f;        // right col
    }

    // quantize the 9 depthwise weights: sign(w) * 2^clip(round(log2|w|), -14, 0)
    if (tid < 9) {
        float v  = wgt[c * 9 + tid];
        float s  = (v > 0.f) ? 1.f : ((v < 0.f) ? -1.f : 0.f);
        float sh = rintf(log2f(fabsf(v) + 1e-45f));   // rintf = round-half-even (matches jnp.round)
        sh = fminf(fmaxf(sh, -14.f), 0.f);
        wq[tid] = s * exp2f(sh);
    }

    // stage quantized input plane into padded LDS tile (float4 global loads)
    const float4* __restrict__ xp = (const float4*)(x + (size_t)plane * HWP);
    for (int i = tid; i < NF4; i += 256) {
        float4 v = xp[i];
        // round_to_fixed: floor to 2^-16 grid, clamp [-2^15, 2^15-1]
        v.x = fminf(fmaxf(floorf(v.x * 65536.f) * (1.f / 65536.f), -32768.f), 32767.f);
        v.y = fminf(fmaxf(floorf(v.y * 65536.f) * (1.f / 65536.f), -32768.f), 32767.f);
        v.z = fminf(fmaxf(floorf(v.z * 65536.f) * (1.f / 65536.f), -32768.f), 32767.f);
        v.w = fminf(fmaxf(floorf(v.w * 65536.f) * (1.f / 65536.f), -32768.f), 32767.f);
        int p  = i * 4;
        int h  = p / W56;
        int wc = p - h * W56;
        float* dst = &tile[(h + 1) * PITCH + wc + 1];
        dst[0] = v.x; dst[1] = v.y; dst[2] = v.z; dst[3] = v.w;
    }
    __syncthreads();

    // compute: 4 consecutive outputs per thread from 3 rows x 6 cols of LDS
    const float w00 = wq[0], w01 = wq[1], w02 = wq[2];
    const float w10 = wq[3], w11 = wq[4], w12 = wq[5];
    const float w20 = wq[6], w21 = wq[7], w22 = wq[8];

    float4* __restrict__ op = (float4*)(out + (size_t)plane * HWP);
    for (int j = tid; j < NF4; j += 256) {
        int p  = j * 4;
        int h  = p / W56;
        int wc = p - h * W56;
        float4 o = make_float4(0.f, 0.f, 0.f, 0.f);
        #pragma unroll
        for (int dh = 0; dh < 3; ++dh) {
            const float* r = &tile[(h + dh) * PITCH + wc];
            float r0 = r[0], r1 = r[1], r2 = r[2];
            float r3 = r[3], r4 = r[4], r5 = r[5];
            float a, b, cc;
            if (dh == 0)      { a = w00; b = w01; cc = w02; }
            else if (dh == 1) { a = w10; b = w11; cc = w12; }
            else              { a = w20; b = w21; cc = w22; }
            o.x = fmaf(a, r0, fmaf(b, r1, fmaf(cc, r2, o.x)));
            o.y = fmaf(a, r1, fmaf(b, r2, fmaf(cc, r3, o.y)));
            o.z = fmaf(a, r2, fmaf(b, r3, fmaf(cc, r4, o.z)));
            o.w = fmaf(a, r3, fmaf(b, r4, fmaf(cc, r5, o.w)));
        }
        op[j] = o;
    }
}

extern "C" void kernel_launch(void* const* d_in, const int* in_sizes, int n_in,
                              void* d_out, int out_size, void* d_ws, size_t ws_size,
                              hipStream_t stream) {
    const float* x   = (const float*)d_in[0];
    const float* wgt = (const float*)d_in[1];
    float* out       = (float*)d_out;

    const int planes = out_size / HWP;          // B*C = 12288
    const int C      = in_sizes[1] / 9;         // 384 (weight is C*1*3*3)

    dwconv3x3_q<<<planes, 256, 0, stream>>>(x, wgt, out, C);
}